// Round 5
// baseline (143.554 us; speedup 1.0000x reference)
//
#include <hip/hip_runtime.h>
#include <hip/hip_bf16.h>

typedef __attribute__((ext_vector_type(8))) short bf16x8;
typedef __attribute__((ext_vector_type(4))) float f32x4;
typedef __attribute__((ext_vector_type(8))) unsigned short ushort8;

#define HW 4096
#define NC 64
#define PROWS 4356  // 66*66 padded rows

static __device__ __forceinline__ unsigned short f2bf(float f) {
    unsigned int u = __float_as_uint(f);
    unsigned int r = (u + 0x7FFFu + ((u >> 16) & 1u)) >> 16;
    return (unsigned short)r;
}

// ---------------- conv 1x1: qkv_raw[b][oc][n] = sum_ic w[oc][ic]*x[b][ic][n]
__global__ __launch_bounds__(256) void k_conv1x1(const float* __restrict__ x,
                                                 const float* __restrict__ wqkv,
                                                 float* __restrict__ out) {
    __shared__ float wl[512]; // 8 oc x 64 ic
    int nb = blockIdx.x, ocg = blockIdx.y, b = blockIdx.z;
    int t = threadIdx.x;
    for (int i = t; i < 512; i += 256) wl[i] = wqkv[ocg * 512 + i];
    __syncthreads();
    int n = nb * 256 + t;
    const float* xb = x + (size_t)b * NC * HW + n;
    float acc[8] = {0.f,0.f,0.f,0.f,0.f,0.f,0.f,0.f};
    for (int ic = 0; ic < 64; ic++) {
        float xv = xb[(size_t)ic * HW];
        #pragma unroll
        for (int o = 0; o < 8; o++) acc[o] += wl[o * 64 + ic] * xv;
    }
    float* ob = out + (size_t)b * 192 * HW + (size_t)(ocg * 8) * HW + n;
    #pragma unroll
    for (int o = 0; o < 8; o++) ob[(size_t)o * HW] = acc[o];
}

// ---------------- depthwise 3x3 SAME
__global__ __launch_bounds__(256) void k_dwconv(const float* __restrict__ in,
                                                const float* __restrict__ wdw,
                                                float* __restrict__ out) {
    int yg = blockIdx.x, ch = blockIdx.y, b = blockIdx.z;
    int t = threadIdx.x;
    int y = yg * 4 + (t >> 6), xx = t & 63;
    const float* ib = in + ((size_t)b * 192 + ch) * HW;
    const float* wp = wdw + ch * 9;
    float s = 0.f;
    #pragma unroll
    for (int dy = 0; dy < 3; dy++) {
        int yy = y + dy - 1;
        if (yy < 0 || yy > 63) continue;
        const float* r = ib + yy * 64;
        float v0 = (xx > 0) ? r[xx - 1] : 0.f;
        float v1 = r[xx];
        float v2 = (xx < 63) ? r[xx + 1] : 0.f;
        const float* wr = wp + dy * 3;
        s += wr[0] * v0 + wr[1] * v1 + wr[2] * v2;
    }
    out[((size_t)b * 192 + ch) * HW + y * 64 + xx] = s;
}

// ---------------- per-(b,ch) inverse L2 norm over hw for q,k
__global__ __launch_bounds__(256) void k_norms(const float* __restrict__ qkv,
                                               float* __restrict__ invn) {
    int ch = blockIdx.x, b = blockIdx.y;
    const float* p = qkv + ((size_t)b * 192 + ch) * HW;
    float s = 0.f;
    for (int i = threadIdx.x; i < HW; i += 256) { float v = p[i]; s += v * v; }
    #pragma unroll
    for (int m = 1; m < 64; m <<= 1) s += __shfl_xor(s, m);
    __shared__ float red[4];
    if ((threadIdx.x & 63) == 0) red[threadIdx.x >> 6] = s;
    __syncthreads();
    if (threadIdx.x == 0) {
        float tot = red[0] + red[1] + red[2] + red[3];
        float nrm = sqrtf(tot);
        invn[b * 128 + ch] = 1.f / fmaxf(nrm, 1e-12f);
    }
}

// ---------------- pack: qT/kT[b][n][c] (normalized, bf16), vn[b][c][n] (bf16)
__global__ __launch_bounds__(256) void k_pack(const float* __restrict__ qkv,
                                              const float* __restrict__ invn,
                                              unsigned short* __restrict__ qT,
                                              unsigned short* __restrict__ kT,
                                              unsigned short* __restrict__ vn) {
    int nb = blockIdx.x, sel = blockIdx.y, b = blockIdx.z;
    int n = nb * 256 + threadIdx.x;
    if (sel == 2) {
        const float* src = qkv + ((size_t)b * 192 + 128) * HW + n;
        unsigned short* dst = vn + (size_t)b * NC * HW + n;
        for (int c = 0; c < 64; c++) dst[(size_t)c * HW] = f2bf(src[(size_t)c * HW]);
    } else {
        const float* src = qkv + ((size_t)b * 192 + sel * 64) * HW + n;
        const float* iv = invn + b * 128 + sel * 64;
        unsigned short* dst = (sel == 0 ? qT : kT) + ((size_t)b * HW + n) * NC;
        for (int c0 = 0; c0 < 64; c0 += 8) {
            ushort8 pk;
            #pragma unroll
            for (int j = 0; j < 8; j++)
                pk[j] = f2bf(src[(size_t)(c0 + j) * HW] * iv[c0 + j]);
            *reinterpret_cast<ushort8*>(dst + c0) = pk;
        }
    }
}

// ---------------- pass 1: row sums of exp(s); s = cosine in [-1,1] so no max.
// 128 m-rows per block, K-tile double-buffered in XOR-swizzled LDS.
__global__ __launch_bounds__(256) void k_rowsum(const unsigned short* __restrict__ qT,
                                                const unsigned short* __restrict__ kT,
                                                float* __restrict__ part) {
    __shared__ __align__(16) unsigned short klds[2][64 * 64];
    int mblk = blockIdx.x, ns = blockIdx.y, b = blockIdx.z;
    int t = threadIdx.x;
    int w = t >> 6, lane = t & 63, g = lane >> 4, r15 = lane & 15;
    const unsigned short* qb = qT + (size_t)b * HW * NC;
    const unsigned short* kb = kT + (size_t)b * HW * NC;
    int m0 = mblk * 128 + w * 16;
    const unsigned short* qp0 = qb + (size_t)(m0 + r15) * NC + g * 8;
    const unsigned short* qp1 = qb + (size_t)(m0 + 64 + r15) * NC + g * 8;
    bf16x8 a0 = *reinterpret_cast<const bf16x8*>(qp0);
    bf16x8 a1 = *reinterpret_cast<const bf16x8*>(qp0 + 32);
    bf16x8 a2 = *reinterpret_cast<const bf16x8*>(qp1);
    bf16x8 a3 = *reinterpret_cast<const bf16x8*>(qp1 + 32);
    float sa[4] = {0.f, 0.f, 0.f, 0.f};
    float sb[4] = {0.f, 0.f, 0.f, 0.f};
    int nbase = ns * 512;
    int nl = t >> 2, seg = t & 3;
    int hs = nl & 7;
    int c0s = (2 * seg) ^ hs, c1s = (2 * seg + 1) ^ hs;
    {
        const unsigned short* sp = kb + (size_t)(nbase + nl) * NC + seg * 16;
        *reinterpret_cast<ushort8*>(&klds[0][nl * 64 + c0s * 8]) = *reinterpret_cast<const ushort8*>(sp);
        *reinterpret_cast<ushort8*>(&klds[0][nl * 64 + c1s * 8]) = *reinterpret_cast<const ushort8*>(sp + 8);
    }
    __syncthreads();
    int cur = 0;
    int hr = r15 & 7;
    for (int it = 0; it < 8; it++) {
        ushort8 r0, r1;
        bool hasnext = it < 7;
        if (hasnext) {
            const unsigned short* sp = kb + (size_t)(nbase + (it + 1) * 64 + nl) * NC + seg * 16;
            r0 = *reinterpret_cast<const ushort8*>(sp);
            r1 = *reinterpret_cast<const ushort8*>(sp + 8);
        }
        #pragma unroll
        for (int tt = 0; tt < 4; tt++) {
            int row = tt * 16 + r15;
            bf16x8 b0 = *reinterpret_cast<const bf16x8*>(&klds[cur][row * 64 + ((g    ) ^ hr) * 8]);
            bf16x8 b1 = *reinterpret_cast<const bf16x8*>(&klds[cur][row * 64 + ((g + 4) ^ hr) * 8]);
            f32x4 d0 = {0.f, 0.f, 0.f, 0.f};
            f32x4 d1 = {0.f, 0.f, 0.f, 0.f};
            d0 = __builtin_amdgcn_mfma_f32_16x16x32_bf16(a0, b0, d0, 0, 0, 0);
            d1 = __builtin_amdgcn_mfma_f32_16x16x32_bf16(a2, b0, d1, 0, 0, 0);
            d0 = __builtin_amdgcn_mfma_f32_16x16x32_bf16(a1, b1, d0, 0, 0, 0);
            d1 = __builtin_amdgcn_mfma_f32_16x16x32_bf16(a3, b1, d1, 0, 0, 0);
            #pragma unroll
            for (int r = 0; r < 4; r++) { sa[r] += __expf(d0[r]); sb[r] += __expf(d1[r]); }
        }
        if (hasnext) {
            *reinterpret_cast<ushort8*>(&klds[cur ^ 1][nl * 64 + c0s * 8]) = r0;
            *reinterpret_cast<ushort8*>(&klds[cur ^ 1][nl * 64 + c1s * 8]) = r1;
            cur ^= 1;
        }
        __syncthreads();
    }
    #pragma unroll
    for (int off = 1; off < 16; off <<= 1) {
        #pragma unroll
        for (int r = 0; r < 4; r++) {
            sa[r] += __shfl_xor(sa[r], off);
            sb[r] += __shfl_xor(sb[r], off);
        }
    }
    if (r15 == 0) {
        size_t base = ((size_t)ns * 4 + b) * HW;
        f32x4 va = {sa[0], sa[1], sa[2], sa[3]};
        f32x4 vb = {sb[0], sb[1], sb[2], sb[3]};
        *reinterpret_cast<f32x4*>(&part[base + m0 + g * 4]) = va;
        *reinterpret_cast<f32x4*>(&part[base + m0 + 64 + g * 4]) = vb;
    }
}

// ---------------- rowinv = 1 / sum of 8 partials
__global__ __launch_bounds__(256) void k_recip(const float* __restrict__ part,
                                               float* __restrict__ inv) {
    int i = blockIdx.x * 256 + threadIdx.x;  // 16384 = 4*HW
    float s = 0.f;
    #pragma unroll
    for (int ns = 0; ns < 8; ns++) s += part[i + ns * 4 * HW];
    inv[i] = 1.f / s;
}

// ---------------- fused pass 2: full-m per block, n-block of 32.
// out[c, n] = sum_m v[c,m] exp(s[m,n]) / D[m]; writes bf16 transposed+padded inP directly.
__global__ __launch_bounds__(256) void k_attn_fused(const unsigned short* __restrict__ qT,
                                                    const unsigned short* __restrict__ kT,
                                                    const unsigned short* __restrict__ vn,
                                                    const float* __restrict__ rowinv,
                                                    unsigned short* __restrict__ inP) {
    __shared__ __align__(16) unsigned short klds[32 * 64];
    __shared__ __align__(16) unsigned short plds[2][32 * 64];
    int nb = blockIdx.x, b = blockIdx.y;
    int t = threadIdx.x;
    int w = t >> 6, lane = t & 63, g = lane >> 4, r15 = lane & 15;
    int n0 = nb * 32;
    const unsigned short* qb = qT + (size_t)b * HW * NC;
    const unsigned short* kb = kT + (size_t)b * HW * NC;
    const unsigned short* vb = vn + (size_t)b * NC * HW;
    const float* rib = rowinv + (size_t)b * HW;
    // stage K tile: 32 rows x 64 cols bf16, 16B-chunk XOR swizzle by row&7
    {
        int nl = t >> 3, ck = t & 7;
        ushort8 v = *reinterpret_cast<const ushort8*>(kb + (size_t)(n0 + nl) * NC + ck * 8);
        *reinterpret_cast<ushort8*>(&klds[nl * 64 + (ck ^ (nl & 7)) * 8]) = v;
    }
    __syncthreads();
    f32x4 acc[2] = {{0.f,0.f,0.f,0.f},{0.f,0.f,0.f,0.f}};
    int mrow = w * 16 + r15;
    int hr = r15 & 7;
    // prologue: iter-0 operands
    const unsigned short* qp = qb + (size_t)mrow * NC + g * 8;
    bf16x8 qa0 = *reinterpret_cast<const bf16x8*>(qp);
    bf16x8 qa1 = *reinterpret_cast<const bf16x8*>(qp + 32);
    const unsigned short* vrow = vb + (size_t)mrow * HW;
    bf16x8 va0 = *reinterpret_cast<const bf16x8*>(vrow + g * 8);
    bf16x8 va1 = *reinterpret_cast<const bf16x8*>(vrow + 32 + g * 8);
    float pinv[4];
    #pragma unroll
    for (int r = 0; r < 4; r++) pinv[r] = rib[w * 16 + g * 4 + r];
    int cur = 0;
    for (int it = 0; it < 64; it++) {
        int mb = it * 64;
        // S-phase: S[m, n] tiles + exp + pack to plds[cur]
        #pragma unroll
        for (int tt = 0; tt < 2; tt++) {
            int row = tt * 16 + r15;
            bf16x8 b0 = *reinterpret_cast<const bf16x8*>(&klds[row * 64 + ((g    ) ^ hr) * 8]);
            bf16x8 b1 = *reinterpret_cast<const bf16x8*>(&klds[row * 64 + ((g + 4) ^ hr) * 8]);
            f32x4 d = {0.f, 0.f, 0.f, 0.f};
            d = __builtin_amdgcn_mfma_f32_16x16x32_bf16(qa0, b0, d, 0, 0, 0);
            d = __builtin_amdgcn_mfma_f32_16x16x32_bf16(qa1, b1, d, 0, 0, 0);
            float p0 = __expf(d[0]) * pinv[0];
            float p1 = __expf(d[1]) * pinv[1];
            float p2 = __expf(d[2]) * pinv[2];
            float p3 = __expf(d[3]) * pinv[3];
            unsigned int lo, hi;
            asm("v_cvt_pk_bf16_f32 %0, %1, %2" : "=v"(lo) : "v"(p0), "v"(p1));
            asm("v_cvt_pk_bf16_f32 %0, %1, %2" : "=v"(hi) : "v"(p2), "v"(p3));
            // P stored [n-local row][m-local col]: col shorts = w*16+g*4 -> chunk 2w+(g>>1)
            int ck = (2 * w + (g >> 1)) ^ hr;
            uint2 pk; pk.x = lo; pk.y = hi;
            *reinterpret_cast<uint2*>(
                reinterpret_cast<char*>(&plds[cur][row * 64]) + ck * 16 + (g & 1) * 8) = pk;
        }
        // prefetch next-iter Q/V/pinv (hidden under S + sync)
        bf16x8 qn0 = qa0, qn1 = qa1, vn0 = va0, vn1 = va1;
        float pinvn[4] = {pinv[0], pinv[1], pinv[2], pinv[3]};
        if (it < 63) {
            const unsigned short* qn = qb + (size_t)(mb + 64 + mrow) * NC + g * 8;
            qn0 = *reinterpret_cast<const bf16x8*>(qn);
            qn1 = *reinterpret_cast<const bf16x8*>(qn + 32);
            vn0 = *reinterpret_cast<const bf16x8*>(vrow + mb + 64 + g * 8);
            vn1 = *reinterpret_cast<const bf16x8*>(vrow + mb + 96 + g * 8);
            #pragma unroll
            for (int r = 0; r < 4; r++) pinvn[r] = rib[mb + 64 + w * 16 + g * 4 + r];
        }
        __syncthreads();
        // PV-phase: acc[tt] += V[:, m-tile] * P[m-tile, n]
        #pragma unroll
        for (int tt = 0; tt < 2; tt++) {
            int row = tt * 16 + r15;
            bf16x8 p0 = *reinterpret_cast<const bf16x8*>(&plds[cur][row * 64 + ((g    ) ^ hr) * 8]);
            bf16x8 p1 = *reinterpret_cast<const bf16x8*>(&plds[cur][row * 64 + ((g + 4) ^ hr) * 8]);
            acc[tt] = __builtin_amdgcn_mfma_f32_16x16x32_bf16(va0, p0, acc[tt], 0, 0, 0);
            acc[tt] = __builtin_amdgcn_mfma_f32_16x16x32_bf16(va1, p1, acc[tt], 0, 0, 0);
        }
        qa0 = qn0; qa1 = qn1; va0 = vn0; va1 = vn1;
        #pragma unroll
        for (int r = 0; r < 4; r++) pinv[r] = pinvn[r];
        cur ^= 1;
    }
    // write bf16 to padded transposed inP: pixel n = n0 + tt*16 + r15, channel c = w*16+g*4+r
    int y = nb >> 1;
    #pragma unroll
    for (int tt = 0; tt < 2; tt++) {
        int x = (nb & 1) * 32 + tt * 16 + r15;
        unsigned short* dst = inP + ((size_t)b * PROWS + (size_t)(y + 1) * 66 + 1 + x) * 64 + w * 16 + g * 4;
        unsigned int lo, hi;
        asm("v_cvt_pk_bf16_f32 %0, %1, %2" : "=v"(lo) : "v"(acc[tt][0]), "v"(acc[tt][1]));
        asm("v_cvt_pk_bf16_f32 %0, %1, %2" : "=v"(hi) : "v"(acc[tt][2]), "v"(acc[tt][3]));
        uint2 pk; pk.x = lo; pk.y = hi;
        *reinterpret_cast<uint2*>(dst) = pk;
    }
}

// ---------------- zero-fill padded transposed buffer
__global__ __launch_bounds__(256) void k_zero(float4* __restrict__ p, int n4) {
    int i = blockIdx.x * 256 + threadIdx.x;
    if (i < n4) p[i] = make_float4(0.f, 0.f, 0.f, 0.f);
}

// ---------------- weights fp32 OIHW -> bf16 [tap][oc][ic]
__global__ __launch_bounds__(256) void k_wconv(const float* __restrict__ wp,
                                               unsigned short* __restrict__ wbf) {
    int idx = blockIdx.x * 256 + threadIdx.x;  // 36864 total
    int tap = idx >> 12;
    int rem = idx & 4095;
    int oc = rem >> 6, ic = rem & 63;
    wbf[idx] = f2bf(wp[(oc * 64 + ic) * 9 + tap]);
}

// ---------------- proj conv 3x3 via MFMA: 9 shifted GEMMs
__global__ __launch_bounds__(256) void k_proj_mfma(const unsigned short* __restrict__ inP,
                                                   const unsigned short* __restrict__ wbf,
                                                   float* __restrict__ out) {
    int nb = blockIdx.x, b = blockIdx.y;
    int t = threadIdx.x;
    int w = t >> 6, lane = t & 63, g = lane >> 4, r15 = lane & 15;
    int y = nb >> 1;
    int x0 = (nb & 1) * 32 + (w & 1) * 16;
    int oc0 = (w >> 1) * 32;
    const unsigned short* base = inP + (size_t)b * PROWS * 64;
    f32x4 acc[2] = {{0.f,0.f,0.f,0.f},{0.f,0.f,0.f,0.f}};
    #pragma unroll
    for (int tap = 0; tap < 9; tap++) {
        int dy = tap / 3, dx = tap % 3;
        int p = (y + dy) * 66 + x0 + dx + r15;
        const unsigned short* bp = base + (size_t)p * 64 + g * 8;
        bf16x8 b0 = *reinterpret_cast<const bf16x8*>(bp);
        bf16x8 b1 = *reinterpret_cast<const bf16x8*>(bp + 32);
        #pragma unroll
        for (int tt = 0; tt < 2; tt++) {
            const unsigned short* ap = wbf + tap * 4096 + (size_t)(oc0 + tt * 16 + r15) * 64 + g * 8;
            bf16x8 a0 = *reinterpret_cast<const bf16x8*>(ap);
            bf16x8 a1 = *reinterpret_cast<const bf16x8*>(ap + 32);
            acc[tt] = __builtin_amdgcn_mfma_f32_16x16x32_bf16(a0, b0, acc[tt], 0, 0, 0);
            acc[tt] = __builtin_amdgcn_mfma_f32_16x16x32_bf16(a1, b1, acc[tt], 0, 0, 0);
        }
    }
    int n0 = y * 64 + x0;
    #pragma unroll
    for (int tt = 0; tt < 2; tt++) {
        #pragma unroll
        for (int r = 0; r < 4; r++)
            out[((size_t)b * 64 + oc0 + tt * 16 + g * 4 + r) * HW + n0 + r15] = acc[tt][r];
    }
}

extern "C" void kernel_launch(void* const* d_in, const int* in_sizes, int n_in,
                              void* d_out, int out_size, void* d_ws, size_t ws_size,
                              hipStream_t stream) {
    const float* x    = (const float*)d_in[0];
    const float* wqkv = (const float*)d_in[1];
    const float* wdw  = (const float*)d_in[2];
    const float* wprj = (const float*)d_in[3];
    char* ws = (char*)d_ws;
    float* qkv_raw       = (float*)(ws + 0);          // dead after dwconv
    float* qkv           = (float*)(ws + 12582912);   // dead after pack
    unsigned short* qT   = (unsigned short*)(ws + 25165824);
    unsigned short* kT   = (unsigned short*)(ws + 27262976);
    unsigned short* vn   = (unsigned short*)(ws + 29360128);
    float* invn          = (float*)(ws + 31457280);   // 2048 B
    float* rowsum_part   = (float*)(ws + 31459328);   // 524,288 B (8 partials)
    float* rowinv        = (float*)(ws + 31983616);   // 65,536 B
    unsigned short* wbf  = (unsigned short*)(ws + 32049152);  // 73,728 B
    unsigned short* inP  = (unsigned short*)(ws + 32122880);  // 2,230,272 B -> ends 34,353,152

    int inP4 = (4 * PROWS * 64 * 2) / 16;  // 139392 float4
    k_zero       <<<dim3((inP4 + 255) / 256), 256, 0, stream>>>((float4*)inP, inP4);
    k_wconv      <<<dim3(144),        256, 0, stream>>>(wprj, wbf);
    k_conv1x1    <<<dim3(16, 24, 4),  256, 0, stream>>>(x, wqkv, qkv_raw);
    k_dwconv     <<<dim3(16, 192, 4), 256, 0, stream>>>(qkv_raw, wdw, qkv);
    k_norms      <<<dim3(128, 4),     256, 0, stream>>>(qkv, invn);
    k_pack       <<<dim3(16, 3, 4),   256, 0, stream>>>(qkv, invn, qT, kT, vn);
    k_rowsum     <<<dim3(32, 8, 4),   256, 0, stream>>>(qT, kT, rowsum_part);
    k_recip      <<<dim3(64),         256, 0, stream>>>(rowsum_part, rowinv);
    k_attn_fused <<<dim3(128, 4),     256, 0, stream>>>(qT, kT, vn, rowinv, inP);
    k_proj_mfma  <<<dim3(128, 4),     256, 0, stream>>>(inP, wbf, (float*)d_out);
}